// Round 2
// baseline (2141.135 us; speedup 1.0000x reference)
//
#include <hip/hip_runtime.h>
#include <hip/hip_bf16.h>
#include <math.h>

#define K_CODES 8192
#define D_DIM   512
#define N_ROWS  16384
#define DECAYF  0.99f
#define OMDF    0.01f
#define COMMIT  0.25f
#define EPSV    1e-5f

// output offsets (in floats), reference return order:
// z_q_st (8*2048*512), loss (1), indices (8*2048), new_embedding (8192*512),
// ema_cs (8192), ema_es (8192*512)
#define OUT0_OFF 0ull
#define OUT1_OFF 8388608ull
#define OUT2_OFF 8388609ull
#define OUT3_OFF 8404993ull
#define OUT4_OFF 12599297ull
#define OUT5_OFF 12607489ull

#define MT 128
#define NT 128
#define KB 32
#define SPLIT 4
#define CPS (K_CODES / SPLIT)      // 2048 codes per split
#define LDS_STRIDE (MT + 4)        // 132: pad to break 128-stride bank conflicts

// ---------------- exact numpy pairwise sum of squares, n=512 ----------------
// numpy: pairwise(512) = (pairwise(128)+pairwise(128)) + (pairwise(128)+pairwise(128))
// base n=128: r[j]=p[j]; 15 strided adds; ((r0+r1)+(r2+r3))+((r4+r5)+(r6+r7)).
// Products rounded individually (no FMA) -> __fmul_rn/__fadd_rn only.
__device__ __forceinline__ float np_sq_pairwise_512(const float* __restrict__ a) {
    float B[4];
#pragma unroll
    for (int b = 0; b < 4; b++) {
        const float* p = a + b * 128;
        float r[8];
        {
            float4 v0 = *(const float4*)(p);
            float4 v1 = *(const float4*)(p + 4);
            r[0] = __fmul_rn(v0.x, v0.x); r[1] = __fmul_rn(v0.y, v0.y);
            r[2] = __fmul_rn(v0.z, v0.z); r[3] = __fmul_rn(v0.w, v0.w);
            r[4] = __fmul_rn(v1.x, v1.x); r[5] = __fmul_rn(v1.y, v1.y);
            r[6] = __fmul_rn(v1.z, v1.z); r[7] = __fmul_rn(v1.w, v1.w);
        }
        for (int i = 8; i < 128; i += 8) {
            float4 w0 = *(const float4*)(p + i);
            float4 w1 = *(const float4*)(p + i + 4);
            r[0] = __fadd_rn(r[0], __fmul_rn(w0.x, w0.x));
            r[1] = __fadd_rn(r[1], __fmul_rn(w0.y, w0.y));
            r[2] = __fadd_rn(r[2], __fmul_rn(w0.z, w0.z));
            r[3] = __fadd_rn(r[3], __fmul_rn(w0.w, w0.w));
            r[4] = __fadd_rn(r[4], __fmul_rn(w1.x, w1.x));
            r[5] = __fadd_rn(r[5], __fmul_rn(w1.y, w1.y));
            r[6] = __fadd_rn(r[6], __fmul_rn(w1.z, w1.z));
            r[7] = __fadd_rn(r[7], __fmul_rn(w1.w, w1.w));
        }
        B[b] = __fadd_rn(__fadd_rn(__fadd_rn(r[0], r[1]), __fadd_rn(r[2], r[3])),
                         __fadd_rn(__fadd_rn(r[4], r[5]), __fadd_rn(r[6], r[7])));
    }
    return __fadd_rn(__fadd_rn(B[0], B[1]), __fadd_rn(B[2], B[3]));
}

__global__ void e2_np_kernel(const float* __restrict__ E, float* __restrict__ e2) {
    int k = blockIdx.x * 256 + threadIdx.x;
    if (k < K_CODES) e2[k] = np_sq_pairwise_512(E + (size_t)k * D_DIM);
}

__global__ void z2_np_kernel(const float* __restrict__ z, float* __restrict__ z2) {
    int r = blockIdx.x * 256 + threadIdx.x;
    if (r < N_ROWS) z2[r] = np_sq_pairwise_512(z + (size_t)r * D_DIM);
}

// ---------------- fused distance GEMM + argmin ----------------
// Emulates numpy fp32: dist = fl( fl(z2 - 2*dot) + e2 ), argmin first-occurrence.
__global__ __launch_bounds__(256, 2) void argmin_kernel(
    const float* __restrict__ z, const float* __restrict__ E,
    const float* __restrict__ e2, const float* __restrict__ z2buf,
    float* __restrict__ wsv, int* __restrict__ wsi)
{
    __shared__ float zs[KB][LDS_STRIDE];
    __shared__ float es[KB][LDS_STRIDE];
    const int nbm = N_ROWS / MT;          // 128 row-blocks
    int bm = blockIdx.x % nbm;
    int sp = blockIdx.x / nbm;
    int row0 = bm * MT;
    int code0 = sp * CPS;
    int tid = threadIdx.x;
    int tx = tid & 15, ty = tid >> 4;

    float z2r[8];
#pragma unroll
    for (int i = 0; i < 8; i++) z2r[i] = z2buf[row0 + ty * 8 + i];

    float best[8];
    int   bidx[8];
#pragma unroll
    for (int i = 0; i < 8; i++) { best[i] = 1e30f; bidx[i] = 0; }

    for (int ct = 0; ct < CPS; ct += NT) {
        float acc[8][8];
#pragma unroll
        for (int i = 0; i < 8; i++) {
#pragma unroll
            for (int j = 0; j < 8; j++) acc[i][j] = 0.f;
        }

        for (int kb = 0; kb < D_DIM; kb += KB) {
            __syncthreads();   // protect previous tile reads
#pragma unroll
            for (int l = 0; l < 4; l++) {
                int t = tid + l * 256;      // 0..1023
                int r = t >> 3;             // 0..127
                int c = (t & 7) << 2;       // 0,4,...,28
                float4 v = *(const float4*)(z + (size_t)(row0 + r) * D_DIM + kb + c);
                zs[c + 0][r] = v.x; zs[c + 1][r] = v.y;
                zs[c + 2][r] = v.z; zs[c + 3][r] = v.w;
                float4 w = *(const float4*)(E + (size_t)(code0 + ct + r) * D_DIM + kb + c);
                es[c + 0][r] = w.x; es[c + 1][r] = w.y;
                es[c + 2][r] = w.z; es[c + 3][r] = w.w;
            }
            __syncthreads();
#pragma unroll 8
            for (int kk = 0; kk < KB; kk++) {
                float a[8], b[8];
                *(float4*)&a[0] = *(const float4*)&zs[kk][ty * 8];
                *(float4*)&a[4] = *(const float4*)&zs[kk][ty * 8 + 4];
                *(float4*)&b[0] = *(const float4*)&es[kk][tx * 8];
                *(float4*)&b[4] = *(const float4*)&es[kk][tx * 8 + 4];
#pragma unroll
                for (int i = 0; i < 8; i++) {
#pragma unroll
                    for (int j = 0; j < 8; j++)
                        acc[i][j] = fmaf(a[i], b[j], acc[i][j]);
                }
            }
        }
        // dist = fl(fl(z2 - 2*acc) + e2); ascending code + strict < = first min
#pragma unroll
        for (int j = 0; j < 8; j++) {
            int code = code0 + ct + tx * 8 + j;
            float c2 = e2[code];
#pragma unroll
            for (int i = 0; i < 8; i++) {
                float t1 = __fadd_rn(z2r[i], __fmul_rn(-2.0f, acc[i][j]));
                float v  = __fadd_rn(t1, c2);
                if (v < best[i]) { best[i] = v; bidx[i] = code; }
            }
        }
    }

    // cross-tx reduction (16 partials per row), reuse LDS
    __syncthreads();
    float* rv = &zs[0][0];          // [16][stride 129] values
    int*   ri = (int*)&es[0][0];    // [16][stride 129] indices
#pragma unroll
    for (int i = 0; i < 8; i++) {
        rv[tx * 129 + ty * 8 + i] = best[i];
        ri[tx * 129 + ty * 8 + i] = bidx[i];
    }
    __syncthreads();
    if (tid < MT) {
        int row = tid;
        float bv = rv[row];
        int   bi = ri[row];
#pragma unroll
        for (int t = 1; t < 16; t++) {
            float v = rv[t * 129 + row];
            int  ix = ri[t * 129 + row];
            if (v < bv || (v == bv && ix < bi)) { bv = v; bi = ix; }
        }
        wsv[sp * N_ROWS + row0 + row] = bv;
        wsi[sp * N_ROWS + row0 + row] = bi;
    }
}

// ---------------- combine splits -> final index ----------------
__global__ void combine_kernel(const float* __restrict__ wsv, const int* __restrict__ wsi,
                               int* __restrict__ idx_out, float* __restrict__ out2) {
    int row = blockIdx.x * 256 + threadIdx.x;
    float bv = wsv[row];
    int   bi = wsi[row];
#pragma unroll
    for (int sp = 1; sp < SPLIT; sp++) {
        float v = wsv[sp * N_ROWS + row];
        int  ix = wsi[sp * N_ROWS + row];
        if (v < bv || (v == bv && ix < bi)) { bv = v; bi = ix; }
    }
    idx_out[row] = bi;
    out2[row] = (float)bi;
}

// ---------------- gather z_q, loss, segment-sum scatter ----------------
__global__ void gather_kernel(const float* __restrict__ z, const float* __restrict__ E,
                              const int* __restrict__ idx, float* __restrict__ out0,
                              float* __restrict__ out4_acc, float* __restrict__ out5_acc,
                              float* __restrict__ loss_acc) {
    int row = blockIdx.x;
    int t = threadIdx.x;   // 128
    int k = idx[row];
    int d = t * 4;
    float4 zv = *(const float4*)(z + (size_t)row * D_DIM + d);
    float4 qv = *(const float4*)(E + (size_t)k * D_DIM + d);
    float4 o;
    o.x = __fadd_rn(zv.x, __fsub_rn(qv.x, zv.x));
    o.y = __fadd_rn(zv.y, __fsub_rn(qv.y, zv.y));
    o.z = __fadd_rn(zv.z, __fsub_rn(qv.z, zv.z));
    o.w = __fadd_rn(zv.w, __fsub_rn(qv.w, zv.w));
    *(float4*)(out0 + (size_t)row * D_DIM + d) = o;
    float dx = qv.x - zv.x, dy = qv.y - zv.y, dz = qv.z - zv.z, dw = qv.w - zv.w;
    float s = dx * dx + dy * dy + dz * dz + dw * dw;
#pragma unroll
    for (int off = 32; off; off >>= 1) s += __shfl_down(s, off, 64);
    __shared__ float part[2];
    if ((t & 63) == 0) part[t >> 6] = s;
    __syncthreads();
    if (t == 0) atomicAdd(loss_acc, part[0] + part[1]);
    float* dst = out5_acc + (size_t)k * D_DIM + d;
    atomicAdd(dst + 0, OMDF * zv.x);
    atomicAdd(dst + 1, OMDF * zv.y);
    atomicAdd(dst + 2, OMDF * zv.z);
    atomicAdd(dst + 3, OMDF * zv.w);
    if (t == 0) atomicAdd(out4_acc + k, OMDF);
}

// ---------------- sum of input ema_cluster_size ----------------
__global__ void sum_cs_kernel(const float* __restrict__ cs, float* __restrict__ out_sum) {
    int t = threadIdx.x;  // 256
    float s = 0.f;
    for (int i = t; i < K_CODES; i += 256) s += cs[i];
#pragma unroll
    for (int off = 32; off; off >>= 1) s += __shfl_down(s, off, 64);
    __shared__ float part[4];
    if ((t & 63) == 0) part[t >> 6] = s;
    __syncthreads();
    if (t == 0) out_sum[0] = part[0] + part[1] + part[2] + part[3];
}

// ---------------- EMA finalize + smoothing + new embedding ----------------
__global__ void finalize_kernel(const float* __restrict__ in_cs, const float* __restrict__ in_es,
                                float* __restrict__ out1, float* __restrict__ out3,
                                float* __restrict__ out4, float* __restrict__ out5,
                                const float* __restrict__ s_in, const float* __restrict__ loss_acc) {
    int k = blockIdx.x;
    int t = threadIdx.x;  // 128
    float cs_acc = out4[k];                       // 0.01 * count_k (accumulated)
    float ema_cs = DECAYF * in_cs[k] + cs_acc;
    float n = DECAYF * s_in[0] + OMDF * (float)N_ROWS;  // sum(ema_cs), counts sum exactly N
    float smoothed = (ema_cs + EPSV) / (n + (float)K_CODES * EPSV) * n;
    int d = t * 4;
    float4 esv = *(const float4*)(in_es + (size_t)k * D_DIM + d);
    float4 accv = *(const float4*)(out5 + (size_t)k * D_DIM + d);
    float4 ema;
    ema.x = DECAYF * esv.x + accv.x;
    ema.y = DECAYF * esv.y + accv.y;
    ema.z = DECAYF * esv.z + accv.z;
    ema.w = DECAYF * esv.w + accv.w;
    *(float4*)(out5 + (size_t)k * D_DIM + d) = ema;
    float4 emb;
    emb.x = ema.x / smoothed;
    emb.y = ema.y / smoothed;
    emb.z = ema.z / smoothed;
    emb.w = ema.w / smoothed;
    *(float4*)(out3 + (size_t)k * D_DIM + d) = emb;
    if (t == 0) out4[k] = ema_cs;
    if (k == 0 && t == 0) out1[0] = COMMIT * loss_acc[0] / (float)(N_ROWS * D_DIM);
}

extern "C" void kernel_launch(void* const* d_in, const int* in_sizes, int n_in,
                              void* d_out, int out_size, void* d_ws, size_t ws_size,
                              hipStream_t stream) {
    const float* z     = (const float*)d_in[0];
    const float* E     = (const float*)d_in[1];
    const float* in_cs = (const float*)d_in[2];
    const float* in_es = (const float*)d_in[3];

    float* out  = (float*)d_out;
    float* out0 = out + OUT0_OFF;
    float* out1 = out + OUT1_OFF;
    float* out2 = out + OUT2_OFF;
    float* out3 = out + OUT3_OFF;
    float* out4 = out + OUT4_OFF;
    float* out5 = out + OUT5_OFF;

    char* ws = (char*)d_ws;
    float* e2   = (float*)(ws);                              // 32 KB
    float* z2   = (float*)(ws + 32 * 1024);                  // 64 KB
    float* wsv  = (float*)(ws + 96 * 1024);                  // 256 KB
    int*   wsi  = (int*)  (ws + (96 + 256) * 1024);          // 256 KB
    int*   idxb = (int*)  (ws + (96 + 512) * 1024);          // 64 KB
    float* loss = (float*)(ws + (96 + 512 + 64) * 1024);     // 4 B
    float* s_in = loss + 1;                                  // 4 B

    // zero accumulators every call (harness does not re-poison between replays)
    hipMemsetAsync(out4, 0, K_CODES * sizeof(float), stream);
    hipMemsetAsync(out5, 0, (size_t)K_CODES * D_DIM * sizeof(float), stream);
    hipMemsetAsync(loss, 0, sizeof(float), stream);

    e2_np_kernel<<<K_CODES / 256, 256, 0, stream>>>(E, e2);
    z2_np_kernel<<<N_ROWS / 256, 256, 0, stream>>>(z, z2);
    argmin_kernel<<<(N_ROWS / MT) * SPLIT, 256, 0, stream>>>(z, E, e2, z2, wsv, wsi);
    combine_kernel<<<N_ROWS / 256, 256, 0, stream>>>(wsv, wsi, idxb, out2);
    gather_kernel<<<N_ROWS, 128, 0, stream>>>(z, E, idxb, out0, out4, out5, loss);
    sum_cs_kernel<<<1, 256, 0, stream>>>(in_cs, s_in);
    finalize_kernel<<<K_CODES, 128, 0, stream>>>(in_cs, in_es, out1, out3, out4, out5, s_in, loss);
}

// Round 3
// 1029.440 us; speedup vs baseline: 2.0799x; 2.0799x over previous
//
#include <hip/hip_runtime.h>
#include <hip/hip_bf16.h>
#include <math.h>

#define K_CODES 8192
#define D_DIM   512
#define N_ROWS  16384
#define DECAYF  0.99f
#define OMDF    0.01f
#define COMMIT  0.25f
#define EPSV    1e-5f

// output offsets (in floats), reference return order:
// z_q_st (8*2048*512), loss (1), indices (8*2048), new_embedding (8192*512),
// ema_cs (8192), ema_es (8192*512)
#define OUT0_OFF 0ull
#define OUT1_OFF 8388608ull
#define OUT2_OFF 8388609ull
#define OUT3_OFF 8404993ull
#define OUT4_OFF 12599297ull
#define OUT5_OFF 12607489ull

#define BM 256
#define BN 256
#define BKC 32
#define NCB (K_CODES / BN)   // 32 colblocks
#define NRB (N_ROWS / BM)    // 64 rowblocks

typedef _Float16 f16x8 __attribute__((ext_vector_type(8)));
typedef float    f32x4 __attribute__((ext_vector_type(4)));
typedef unsigned short u16;

#define GLOAD16(srcp, dstp) __builtin_amdgcn_global_load_lds( \
    (const __attribute__((address_space(1))) unsigned int*)(const void*)(srcp), \
    (__attribute__((address_space(3))) unsigned int*)(void*)(dstp), 16, 0, 0)

// ---------------- exact numpy pairwise sum of squares, n=512 ----------------
__device__ __forceinline__ float np_sq_pairwise_512(const float* __restrict__ a) {
    float B[4];
#pragma unroll
    for (int b = 0; b < 4; b++) {
        const float* p = a + b * 128;
        float r[8];
        {
            float4 v0 = *(const float4*)(p);
            float4 v1 = *(const float4*)(p + 4);
            r[0] = __fmul_rn(v0.x, v0.x); r[1] = __fmul_rn(v0.y, v0.y);
            r[2] = __fmul_rn(v0.z, v0.z); r[3] = __fmul_rn(v0.w, v0.w);
            r[4] = __fmul_rn(v1.x, v1.x); r[5] = __fmul_rn(v1.y, v1.y);
            r[6] = __fmul_rn(v1.z, v1.z); r[7] = __fmul_rn(v1.w, v1.w);
        }
        for (int i = 8; i < 128; i += 8) {
            float4 w0 = *(const float4*)(p + i);
            float4 w1 = *(const float4*)(p + i + 4);
            r[0] = __fadd_rn(r[0], __fmul_rn(w0.x, w0.x));
            r[1] = __fadd_rn(r[1], __fmul_rn(w0.y, w0.y));
            r[2] = __fadd_rn(r[2], __fmul_rn(w0.z, w0.z));
            r[3] = __fadd_rn(r[3], __fmul_rn(w0.w, w0.w));
            r[4] = __fadd_rn(r[4], __fmul_rn(w1.x, w1.x));
            r[5] = __fadd_rn(r[5], __fmul_rn(w1.y, w1.y));
            r[6] = __fadd_rn(r[6], __fmul_rn(w1.z, w1.z));
            r[7] = __fadd_rn(r[7], __fmul_rn(w1.w, w1.w));
        }
        B[b] = __fadd_rn(__fadd_rn(__fadd_rn(r[0], r[1]), __fadd_rn(r[2], r[3])),
                         __fadd_rn(__fadd_rn(r[4], r[5]), __fadd_rn(r[6], r[7])));
    }
    return __fadd_rn(__fadd_rn(B[0], B[1]), __fadd_rn(B[2], B[3]));
}

__global__ void e2_np_kernel(const float* __restrict__ E, float* __restrict__ e2) {
    int k = blockIdx.x * 256 + threadIdx.x;
    e2[k] = np_sq_pairwise_512(E + (size_t)k * D_DIM);
}

__global__ void z2_np_kernel(const float* __restrict__ z, float* __restrict__ z2) {
    int r = blockIdx.x * 256 + threadIdx.x;
    z2[r] = np_sq_pairwise_512(z + (size_t)r * D_DIM);
}

// ---------------- hi/lo fp16 split converters ----------------
__global__ void convert_z_kernel(const float* __restrict__ z,
                                 u16* __restrict__ zhi, u16* __restrict__ zlo) {
    size_t t = (size_t)blockIdx.x * 256 + threadIdx.x;   // 1,048,576 tasks x 8 elems
    const float4* src = (const float4*)z + t * 2;
    float4 v0 = src[0], v1 = src[1];
    float vv[8] = {v0.x, v0.y, v0.z, v0.w, v1.x, v1.y, v1.z, v1.w};
    f16x8 hv, lv;
#pragma unroll
    for (int j = 0; j < 8; j++) {
        _Float16 h = (_Float16)vv[j];
        hv[j] = h;
        lv[j] = (_Float16)(vv[j] - (float)h);
    }
    ((f16x8*)zhi)[t] = hv;
    ((f16x8*)zlo)[t] = lv;
}

__global__ void convert_e_kernel(const float* __restrict__ E,
                                 u16* __restrict__ ehi, u16* __restrict__ elo) {
    size_t t = (size_t)blockIdx.x * 256 + threadIdx.x;   // 524,288 tasks x 8 elems
    const float4* src = (const float4*)E + t * 2;
    float4 v0 = src[0], v1 = src[1];
    float vv[8] = {v0.x, v0.y, v0.z, v0.w, v1.x, v1.y, v1.z, v1.w};
    f16x8 hv, lv;
#pragma unroll
    for (int j = 0; j < 8; j++) {
        float s = vv[j] * 4096.0f;     // exact exponent shift
        _Float16 h = (_Float16)s;
        hv[j] = h;
        lv[j] = (_Float16)(s - (float)h);
    }
    ((f16x8*)ehi)[t] = hv;
    ((f16x8*)elo)[t] = lv;
}

// ---------------- MFMA distance GEMM + argmin ----------------
// dist = fl( fl(z2 - acc*2^-11) + e2 ), acc = 3-product split dot * 4096.
__global__ __launch_bounds__(512, 1) void argmin_mfma_kernel(
    const u16* __restrict__ zhi, const u16* __restrict__ zlo,
    const u16* __restrict__ ehi, const u16* __restrict__ elo,
    const float* __restrict__ e2, const float* __restrict__ z2,
    float* __restrict__ pv, int* __restrict__ pi)
{
    // [buf][plane: Ah,Al,Bh,Bl][slot: g*256 + row16run][8 f16] = 128 KB
    __shared__ __align__(16) u16 lds[2][4][1024][8];

    int bid = blockIdx.x;
    int xcd = bid & 7, sub = bid >> 3;       // XCD-chunked swizzle (2048 = 8*256)
    int nb  = xcd * 256 + sub;
    int cb  = nb >> 6;                       // 0..31 colblock
    int rb  = nb & 63;                       // 0..63 rowblock
    int row0 = rb * BM, col0 = cb * BN;

    int tid = threadIdx.x;
    int l   = tid & 63;
    int w   = tid >> 6;
    int mw  = w >> 2, nw = w & 3;            // wave grid 2(m) x 4(n)
    int lg  = l >> 4;                        // k-group 0..3
    int l16 = l & 15;

    f32x4 acc[8][4];
#pragma unroll
    for (int m = 0; m < 8; m++)
#pragma unroll
        for (int n = 0; n < 4; n++)
            acc[m][n] = (f32x4){0.f, 0.f, 0.f, 0.f};

    auto stage_all = [&](int buf, int kb) {
#pragma unroll
        for (int i = 0; i < 2; i++) {
            int slot = tid + i * 512;
            int g = slot >> 8, r = slot & 255;
            int goff = kb + g * 8;
            GLOAD16(zhi + (size_t)(row0 + r) * D_DIM + goff, &lds[buf][0][slot][0]);
            GLOAD16(zlo + (size_t)(row0 + r) * D_DIM + goff, &lds[buf][1][slot][0]);
            GLOAD16(ehi + (size_t)(col0 + r) * D_DIM + goff, &lds[buf][2][slot][0]);
            GLOAD16(elo + (size_t)(col0 + r) * D_DIM + goff, &lds[buf][3][slot][0]);
        }
    };

    stage_all(0, 0);
    __syncthreads();   // drains vmcnt before barrier
    int cur = 0;
    for (int t = 0; t < 16; t++) {
        if (t < 15) stage_all(cur ^ 1, (t + 1) * BKC);
        f16x8 bh[4], bl[4];
#pragma unroll
        for (int n = 0; n < 4; n++) {
            int slot = lg * 256 + nw * 64 + n * 16 + l16;
            bh[n] = *(const f16x8*)&lds[cur][2][slot][0];
            bl[n] = *(const f16x8*)&lds[cur][3][slot][0];
        }
#pragma unroll
        for (int m = 0; m < 8; m++) {
            int slot = lg * 256 + mw * 128 + m * 16 + l16;
            f16x8 ah = *(const f16x8*)&lds[cur][0][slot][0];
            f16x8 al = *(const f16x8*)&lds[cur][1][slot][0];
#pragma unroll
            for (int n = 0; n < 4; n++)
                acc[m][n] = __builtin_amdgcn_mfma_f32_16x16x32_f16(ah, bh[n], acc[m][n], 0, 0, 0);
#pragma unroll
            for (int n = 0; n < 4; n++)
                acc[m][n] = __builtin_amdgcn_mfma_f32_16x16x32_f16(ah, bl[n], acc[m][n], 0, 0, 0);
#pragma unroll
            for (int n = 0; n < 4; n++)
                acc[m][n] = __builtin_amdgcn_mfma_f32_16x16x32_f16(al, bh[n], acc[m][n], 0, 0, 0);
        }
        __syncthreads();   // drains vmcnt+lgkmcnt, protects both buffers
        cur ^= 1;
    }

    // ---- epilogue: distances + first-occurrence argmin ----
    const float nscale = -0.00048828125f;   // -2^-11 (undo 4096 scale, apply -2)
    float e2c[4];
#pragma unroll
    for (int n = 0; n < 4; n++) e2c[n] = e2[col0 + nw * 64 + n * 16 + l16];

    float* redv = (float*)&lds[0][0][0][0];       // [256][4] vals  (4 KB)
    int*   redi = (int*)((char*)redv + 4096);     // [256][4] idx   (4 KB)

#pragma unroll
    for (int m = 0; m < 8; m++) {
#pragma unroll
        for (int r = 0; r < 4; r++) {
            int row = row0 + mw * 128 + m * 16 + lg * 4 + r;
            float z2v = z2[row];
            float bv = 1e30f; int bc = 0x7fffffff;
#pragma unroll
            for (int n = 0; n < 4; n++) {
                int code = col0 + nw * 64 + n * 16 + l16;
                float v = __fadd_rn(__fadd_rn(z2v, __fmul_rn(acc[m][n][r], nscale)), e2c[n]);
                if (v < bv) { bv = v; bc = code; }   // n ascending => code ascending
            }
#pragma unroll
            for (int s = 1; s < 16; s <<= 1) {
                float ov = __shfl_xor(bv, s, 64);
                int   oc = __shfl_xor(bc, s, 64);
                if (ov < bv || (ov == bv && oc < bc)) { bv = ov; bc = oc; }
            }
            if (l16 == r) {
                int rl = mw * 128 + m * 16 + lg * 4 + r;
                redv[rl * 4 + nw] = bv;
                redi[rl * 4 + nw] = bc;
            }
        }
    }
    __syncthreads();
    if (tid < 256) {
        float bv = redv[tid * 4]; int bc = redi[tid * 4];
#pragma unroll
        for (int q = 1; q < 4; q++) {
            float v = redv[tid * 4 + q]; int c = redi[tid * 4 + q];
            if (v < bv || (v == bv && c < bc)) { bv = v; bc = c; }
        }
        pv[(size_t)cb * N_ROWS + row0 + tid] = bv;
        pi[(size_t)cb * N_ROWS + row0 + tid] = bc;
    }
}

// ---------------- combine colblock partials -> final index ----------------
__global__ void combine_kernel(const float* __restrict__ pv, const int* __restrict__ pi,
                               int* __restrict__ idx_out, float* __restrict__ out2) {
    int row = blockIdx.x * 256 + threadIdx.x;
    float bv = pv[row];
    int   bi = pi[row];
#pragma unroll 4
    for (int cb = 1; cb < NCB; cb++) {
        float v = pv[(size_t)cb * N_ROWS + row];
        int   c = pi[(size_t)cb * N_ROWS + row];
        if (v < bv || (v == bv && c < bi)) { bv = v; bi = c; }
    }
    idx_out[row] = bi;
    out2[row] = (float)bi;
}

// ---------------- gather z_q, loss, segment-sum scatter ----------------
__global__ void gather_kernel(const float* __restrict__ z, const float* __restrict__ E,
                              const int* __restrict__ idx, float* __restrict__ out0,
                              float* __restrict__ out4_acc, float* __restrict__ out5_acc,
                              float* __restrict__ loss_acc) {
    int row = blockIdx.x;
    int t = threadIdx.x;   // 128
    int k = idx[row];
    int d = t * 4;
    float4 zv = *(const float4*)(z + (size_t)row * D_DIM + d);
    float4 qv = *(const float4*)(E + (size_t)k * D_DIM + d);
    float4 o;
    o.x = __fadd_rn(zv.x, __fsub_rn(qv.x, zv.x));
    o.y = __fadd_rn(zv.y, __fsub_rn(qv.y, zv.y));
    o.z = __fadd_rn(zv.z, __fsub_rn(qv.z, zv.z));
    o.w = __fadd_rn(zv.w, __fsub_rn(qv.w, zv.w));
    *(float4*)(out0 + (size_t)row * D_DIM + d) = o;
    float dx = qv.x - zv.x, dy = qv.y - zv.y, dz = qv.z - zv.z, dw = qv.w - zv.w;
    float s = dx * dx + dy * dy + dz * dz + dw * dw;
#pragma unroll
    for (int off = 32; off; off >>= 1) s += __shfl_down(s, off, 64);
    __shared__ float part[2];
    if ((t & 63) == 0) part[t >> 6] = s;
    __syncthreads();
    if (t == 0) atomicAdd(loss_acc, part[0] + part[1]);
    float* dst = out5_acc + (size_t)k * D_DIM + d;
    atomicAdd(dst + 0, OMDF * zv.x);
    atomicAdd(dst + 1, OMDF * zv.y);
    atomicAdd(dst + 2, OMDF * zv.z);
    atomicAdd(dst + 3, OMDF * zv.w);
    if (t == 0) atomicAdd(out4_acc + k, OMDF);
}

// ---------------- sum of input ema_cluster_size ----------------
__global__ void sum_cs_kernel(const float* __restrict__ cs, float* __restrict__ out_sum) {
    int t = threadIdx.x;  // 256
    float s = 0.f;
    for (int i = t; i < K_CODES; i += 256) s += cs[i];
#pragma unroll
    for (int off = 32; off; off >>= 1) s += __shfl_down(s, off, 64);
    __shared__ float part[4];
    if ((t & 63) == 0) part[t >> 6] = s;
    __syncthreads();
    if (t == 0) out_sum[0] = part[0] + part[1] + part[2] + part[3];
}

// ---------------- EMA finalize + smoothing + new embedding ----------------
__global__ void finalize_kernel(const float* __restrict__ in_cs, const float* __restrict__ in_es,
                                float* __restrict__ out1, float* __restrict__ out3,
                                float* __restrict__ out4, float* __restrict__ out5,
                                const float* __restrict__ s_in, const float* __restrict__ loss_acc) {
    int k = blockIdx.x;
    int t = threadIdx.x;  // 128
    float cs_acc = out4[k];                       // 0.01 * count_k (accumulated)
    float ema_cs = DECAYF * in_cs[k] + cs_acc;
    float n = DECAYF * s_in[0] + OMDF * (float)N_ROWS;
    float smoothed = (ema_cs + EPSV) / (n + (float)K_CODES * EPSV) * n;
    int d = t * 4;
    float4 esv = *(const float4*)(in_es + (size_t)k * D_DIM + d);
    float4 accv = *(const float4*)(out5 + (size_t)k * D_DIM + d);
    float4 ema;
    ema.x = DECAYF * esv.x + accv.x;
    ema.y = DECAYF * esv.y + accv.y;
    ema.z = DECAYF * esv.z + accv.z;
    ema.w = DECAYF * esv.w + accv.w;
    *(float4*)(out5 + (size_t)k * D_DIM + d) = ema;
    float4 emb;
    emb.x = ema.x / smoothed;
    emb.y = ema.y / smoothed;
    emb.z = ema.z / smoothed;
    emb.w = ema.w / smoothed;
    *(float4*)(out3 + (size_t)k * D_DIM + d) = emb;
    if (t == 0) out4[k] = ema_cs;
    if (k == 0 && t == 0) out1[0] = COMMIT * loss_acc[0] / (float)(N_ROWS * D_DIM);
}

extern "C" void kernel_launch(void* const* d_in, const int* in_sizes, int n_in,
                              void* d_out, int out_size, void* d_ws, size_t ws_size,
                              hipStream_t stream) {
    const float* z     = (const float*)d_in[0];
    const float* E     = (const float*)d_in[1];
    const float* in_cs = (const float*)d_in[2];
    const float* in_es = (const float*)d_in[3];

    float* out  = (float*)d_out;
    float* out0 = out + OUT0_OFF;
    float* out1 = out + OUT1_OFF;
    float* out2 = out + OUT2_OFF;
    float* out3 = out + OUT3_OFF;
    float* out4 = out + OUT4_OFF;
    float* out5 = out + OUT5_OFF;

    // hi/lo fp16 planes stashed in output regions (overwritten later):
    u16* zhi = (u16*)out0;                                   // 16.78 MB
    u16* zlo = zhi + (size_t)N_ROWS * D_DIM;                 // 16.78 MB (out0 exactly)
    u16* ehi = (u16*)(out + OUT3_OFF + 3);                   // +3 floats => 16B aligned
    u16* elo = ehi + (size_t)K_CODES * D_DIM;                // spills 3 floats into out4 (memset later)
    // argmin partials scratch in out5 region (memset happens after combine):
    float* pv = out5;                                        // 32*16384 floats = 2 MB
    int*   pi = (int*)(out5 + (size_t)NCB * N_ROWS);         // 2 MB

    char* ws = (char*)d_ws;
    float* e2   = (float*)(ws);                              // 32 KB
    float* z2   = (float*)(ws + 32 * 1024);                  // 64 KB
    int*   idxb = (int*)  (ws + 96 * 1024);                  // 64 KB
    float* loss = (float*)(ws + 160 * 1024);                 // 4 B
    float* s_in = loss + 1;                                  // 4 B

    convert_z_kernel<<<4096, 256, 0, stream>>>(z, zhi, zlo);
    convert_e_kernel<<<2048, 256, 0, stream>>>(E, ehi, elo);
    e2_np_kernel<<<K_CODES / 256, 256, 0, stream>>>(E, e2);
    z2_np_kernel<<<N_ROWS / 256, 256, 0, stream>>>(z, z2);
    argmin_mfma_kernel<<<NRB * NCB, 512, 0, stream>>>(zhi, zlo, ehi, elo, e2, z2, pv, pi);
    combine_kernel<<<N_ROWS / 256, 256, 0, stream>>>(pv, pi, idxb, out2);

    // zero accumulators (after out5 scratch is consumed; harness doesn't re-poison)
    hipMemsetAsync(out4, 0, K_CODES * sizeof(float), stream);
    hipMemsetAsync(out5, 0, (size_t)K_CODES * D_DIM * sizeof(float), stream);
    hipMemsetAsync(loss, 0, sizeof(float), stream);

    gather_kernel<<<N_ROWS, 128, 0, stream>>>(z, E, idxb, out0, out4, out5, loss);
    sum_cs_kernel<<<1, 256, 0, stream>>>(in_cs, s_in);
    finalize_kernel<<<K_CODES, 128, 0, stream>>>(in_cs, in_es, out1, out3, out4, out5, s_in, loss);
}